// Round 2
// baseline (339.376 us; speedup 1.0000x reference)
//
#include <hip/hip_runtime.h>

typedef unsigned short ushort;
typedef unsigned int uint;
typedef __bf16 bf16x8 __attribute__((ext_vector_type(8)));
typedef float floatx4 __attribute__((ext_vector_type(4)));
typedef float floatx2 __attribute__((ext_vector_type(2)));
typedef ushort ushort8 __attribute__((ext_vector_type(8)));
typedef uint uintx4 __attribute__((ext_vector_type(4)));

constexpr int LQ = 5440;
constexpr int ROWS = 43520;   // batch(8) * 5440

__device__ __forceinline__ ushort f2b(float f) {
  union { float f; uint i; } v; v.f = f;
  uint r = v.i + 0x7FFFu + ((v.i >> 16) & 1u);
  return (ushort)(r >> 16);
}
__device__ __forceinline__ float blo(uint u) {
  union { uint i; float f; } v; v.i = u << 16; return v.f;
}
__device__ __forceinline__ float bhi(uint u) {
  union { uint i; float f; } v; v.i = u & 0xFFFF0000u; return v.f;
}

// ---------------- weight transpose + cast: Wt[n][k] bf16 ----------------
// layout: [0]=Wval(256r) [65536]=Woff(256r)+Wattn(128r) fused 384-row block [163840]=Wout(256r)
__global__ __launch_bounds__(256) void wcast_kernel(
    const float* __restrict__ Wv, const float* __restrict__ Wo,
    const float* __restrict__ Wa, const float* __restrict__ Wu,
    ushort* __restrict__ Wt) {
  int k = threadIdx.x;    // 0..255
  int n = blockIdx.x;     // 0..255
  int m = blockIdx.y;     // 0..3
  const float* src = (m == 0) ? Wv : (m == 1) ? Wo : (m == 2) ? Wa : Wu;
  int N = (m == 2) ? 128 : 256;
  if (n >= N) return;
  size_t off = (size_t)m * 65536 - ((m == 3) ? 32768 : 0);  // 0,65536,131072,163840
  Wt[off + (size_t)n * 256 + k] = f2b(src[(size_t)k * N + n]);
}

// ---------------- 64x128 MFMA mainloop (K=256, BK=32), MFMA-order LDS ----------------
// Wave wv owns n-tiles {2wv, 2wv+1}, all 4 m-tiles. acc[ti][tjj].
template<bool F2B>
__device__ __forceinline__ void tile64_mainloop(
    const void* __restrict__ Av, const ushort* __restrict__ Bt,
    int row_base, int n0, ushort* At, ushort* Bs, floatx4 (&acc)[4][2]) {
  const int t = threadIdx.x;
  const int lane = t & 63, wv = t >> 6;
#pragma unroll
  for (int i = 0; i < 4; ++i)
#pragma unroll
    for (int j = 0; j < 2; ++j) acc[i][j] = floatx4{0.f, 0.f, 0.f, 0.f};

  for (int k0 = 0; k0 < 256; k0 += 32) {
    {
      int r = t >> 2, q = t & 3;       // 256 A-chunks, 1/thread
      int slot = ((r >> 4) * 64 + q * 16 + (r & 15)) * 8;
      if (F2B) {
        const float* ap = (const float*)Av + (size_t)(row_base + r) * 256 + k0 + q * 8;
        float4 a0 = *(const float4*)ap, a1 = *(const float4*)(ap + 4);
        ushort8 u;
        u[0] = f2b(a0.x); u[1] = f2b(a0.y); u[2] = f2b(a0.z); u[3] = f2b(a0.w);
        u[4] = f2b(a1.x); u[5] = f2b(a1.y); u[6] = f2b(a1.z); u[7] = f2b(a1.w);
        *(ushort8*)&At[slot] = u;
      } else {
        const ushort* ap = (const ushort*)Av + (size_t)(row_base + r) * 256 + k0 + q * 8;
        *(ushort8*)&At[slot] = *(const ushort8*)ap;
      }
    }
#pragma unroll
    for (int i = 0; i < 2; ++i) {      // 512 B-chunks, 2/thread
      int item = t + 256 * i;
      int nr = item >> 2, q = item & 3;
      int slot = ((nr >> 4) * 64 + q * 16 + (nr & 15)) * 8;
      *(ushort8*)&Bs[slot] = *(const ushort8*)(Bt + (size_t)(n0 + nr) * 256 + k0 + q * 8);
    }
    __syncthreads();
    bf16x8 af[4], bf[2];
#pragma unroll
    for (int ti = 0; ti < 4; ++ti)
      af[ti] = *(const bf16x8*)&At[(ti * 64 + lane) * 8];
#pragma unroll
    for (int tjj = 0; tjj < 2; ++tjj)
      bf[tjj] = *(const bf16x8*)&Bs[((2 * wv + tjj) * 64 + lane) * 8];
#pragma unroll
    for (int ti = 0; ti < 4; ++ti)
#pragma unroll
      for (int tjj = 0; tjj < 2; ++tjj)
        acc[ti][tjj] = __builtin_amdgcn_mfma_f32_16x16x32_bf16(af[ti], bf[tjj], acc[ti][tjj], 0, 0, 0);
    __syncthreads();
  }
}

// ---------------- K1: value GEMM (fp32 A, f2b in staging) -> bf16 value ----------------
__global__ __launch_bounds__(256) void gemm_val64(
    const float* __restrict__ X, const ushort* __restrict__ WtV,
    const float* __restrict__ bval, ushort* __restrict__ value16) {
  __shared__ ushort At[2048];
  __shared__ ushort Bs[4096];
  floatx4 acc[4][2];
  int row_base = blockIdx.x * 64, n0 = blockIdx.y * 128;
  tile64_mainloop<true>(X, WtV, row_base, n0, At, Bs, acc);
  const int t = threadIdx.x, lane = t & 63, wv = t >> 6;
  const int quad = lane >> 4, l15 = lane & 15;
#pragma unroll
  for (int tjj = 0; tjj < 2; ++tjj) {
    int gcol = n0 + (2 * wv + tjj) * 16 + l15;
    float b = bval[gcol];
#pragma unroll
    for (int ti = 0; ti < 4; ++ti)
#pragma unroll
      for (int reg = 0; reg < 4; ++reg) {
        int grow = row_base + ti * 16 + quad * 4 + reg;
        value16[(size_t)grow * 256 + gcol] = f2b(acc[ti][tjj][reg] + b);
      }
  }
}

// ---------------- K2: off+attn GEMM, head-pair sliced + softmax + slot finalize ----------------
// Block = (row_tile, head-pair hp). B-tiles: off {4hp..4hp+3}, attn {2hp,2hp+1}.
// Wave wv owns m-tile wv. slot = {i00|i01<<16, i10|i11<<16, w00|w01, w10|w11} (bf16*aw)
__global__ __launch_bounds__(256) void gemm_oa_kernel(
    const float* __restrict__ Q, const ushort* __restrict__ WtOA,
    const float* __restrict__ boff, const float* __restrict__ battn,
    const float* __restrict__ refp, uint4* __restrict__ tblq) {
  __shared__ ushort At[2048];
  __shared__ ushort Bs[3072];
  const int t = threadIdx.x;
  const int lane = t & 63, wv = t >> 6;
  const int quad = lane >> 4, l15 = lane & 15;
  const int bx = blockIdx.x;
  const int row_base = (bx % 680) * 64;
  const int hp = bx / 680;            // 0..3
  floatx4 accO[4], accA[2];
#pragma unroll
  for (int p = 0; p < 4; ++p) accO[p] = floatx4{0.f, 0.f, 0.f, 0.f};
#pragma unroll
  for (int q = 0; q < 2; ++q) accA[q] = floatx4{0.f, 0.f, 0.f, 0.f};

  for (int k0 = 0; k0 < 256; k0 += 32) {
    {
      int r = t >> 2, q = t & 3;      // 256 A-chunks
      const float* ap = Q + (size_t)(row_base + r) * 256 + k0 + q * 8;
      float4 a0 = *(const float4*)ap, a1 = *(const float4*)(ap + 4);
      ushort8 u;
      u[0] = f2b(a0.x); u[1] = f2b(a0.y); u[2] = f2b(a0.z); u[3] = f2b(a0.w);
      u[4] = f2b(a1.x); u[5] = f2b(a1.y); u[6] = f2b(a1.z); u[7] = f2b(a1.w);
      *(ushort8*)&At[((r >> 4) * 64 + q * 16 + (r & 15)) * 8] = u;
    }
#pragma unroll
    for (int i = 0; i < 2; ++i) {     // 384 B-chunks
      int item = t + 256 * i;
      if (item < 384) {
        int nrl = item >> 2, q = item & 3;
        int grow_ = (nrl < 64) ? (hp * 64 + nrl) : (256 + hp * 32 + (nrl - 64));
        *(ushort8*)&Bs[((nrl >> 4) * 64 + q * 16 + (nrl & 15)) * 8] =
            *(const ushort8*)(WtOA + (size_t)grow_ * 256 + k0 + q * 8);
      }
    }
    __syncthreads();
    bf16x8 af = *(const bf16x8*)&At[(wv * 64 + lane) * 8];
#pragma unroll
    for (int p = 0; p < 4; ++p) {
      bf16x8 bf = *(const bf16x8*)&Bs[(p * 64 + lane) * 8];
      accO[p] = __builtin_amdgcn_mfma_f32_16x16x32_bf16(af, bf, accO[p], 0, 0, 0);
    }
#pragma unroll
    for (int q = 0; q < 2; ++q) {
      bf16x8 bf = *(const bf16x8*)&Bs[((4 + q) * 64 + lane) * 8];
      accA[q] = __builtin_amdgcn_mfma_f32_16x16x32_bf16(af, bf, accA[q], 0, 0, 0);
    }
    __syncthreads();
  }

  // epilogue: per-thread 8 slot-units (4 reg x 2 heads)
  const int lp = l15, l = lp >> 2;
  const int wd = 64 >> l;
  const int st = (l == 0) ? 0 : (l == 1) ? 4096 : (l == 2) ? 5120 : 5376;
  const float lw = (float)wd;
  const int src = (quad << 4) | (2 * (lp & 7));
  float boO[4], boA[2];
#pragma unroll
  for (int p = 0; p < 4; ++p) boO[p] = boff[(4 * hp + p) * 16 + l15];
#pragma unroll
  for (int q = 0; q < 2; ++q) boA[q] = battn[(2 * hp + q) * 16 + l15];

#pragma unroll
  for (int reg = 0; reg < 4; ++reg) {
    int grow = row_base + wv * 16 + quad * 4 + reg;
    float rx = refp[(size_t)grow * 8 + l * 2];
    float ry = refp[(size_t)grow * 8 + l * 2 + 1];
#pragma unroll
    for (int hh = 0; hh < 2; ++hh) {
      int h = 2 * hp + hh;
      float xa = accA[hh][reg] + boA[hh];
      float m = xa;
      m = fmaxf(m, __shfl_xor(m, 1, 64));
      m = fmaxf(m, __shfl_xor(m, 2, 64));
      m = fmaxf(m, __shfl_xor(m, 4, 64));
      m = fmaxf(m, __shfl_xor(m, 8, 64));
      float e = __expf(xa - m);
      float ssum = e;
      ssum += __shfl_xor(ssum, 1, 64);
      ssum += __shfl_xor(ssum, 2, 64);
      ssum += __shfl_xor(ssum, 4, 64);
      ssum += __shfl_xor(ssum, 8, 64);
      float aw = e / ssum;
      float v0 = accO[2 * hh][reg] + boO[2 * hh];
      float v1 = accO[2 * hh + 1][reg] + boO[2 * hh + 1];
      float x_lo = __shfl(v0, src, 64),     x_hi = __shfl(v1, src, 64);
      float y_lo = __shfl(v0, src | 1, 64), y_hi = __shfl(v1, src | 1, 64);
      float xo = (lp < 8) ? x_lo : x_hi;
      float yo = (lp < 8) ? y_lo : y_hi;
      float X = rx * lw + xo - 0.5f;     // == (ref + off/W)*W - 0.5
      float Y = ry * lw + yo - 0.5f;
      float fx = floorf(X), fy = floorf(Y);
      float lx = X - fx, ly = Y - fy;
      int x0 = (int)fx, y0 = (int)fy, x1 = x0 + 1, y1 = y0 + 1;
      int cx0 = min(max(x0, 0), wd - 1), cx1 = min(max(x1, 0), wd - 1);
      int cy0 = min(max(y0, 0), wd - 1), cy1 = min(max(y1, 0), wd - 1);
      float vx0 = (x0 >= 0 && x0 < wd) ? 1.f : 0.f;
      float vx1 = (x1 >= 0 && x1 < wd) ? 1.f : 0.f;
      float vy0 = (y0 >= 0 && y0 < wd) ? 1.f : 0.f;
      float vy1 = (y1 >= 0 && y1 < wd) ? 1.f : 0.f;
      float g00 = (1.f - lx) * (1.f - ly) * vx0 * vy0 * aw;
      float g01 = lx * (1.f - ly) * vx1 * vy0 * aw;
      float g10 = (1.f - lx) * ly * vx0 * vy1 * aw;
      float g11 = lx * ly * vx1 * vy1 * aw;
      uint i00 = st + cy0 * wd + cx0, i01 = st + cy0 * wd + cx1;
      uint i10 = st + cy1 * wd + cx0, i11 = st + cy1 * wd + cx1;
      uint4 ov;
      ov.x = i00 | (i01 << 16);
      ov.y = i10 | (i11 << 16);
      ov.z = (uint)f2b(g00) | ((uint)f2b(g01) << 16);
      ov.w = (uint)f2b(g10) | ((uint)f2b(g11) << 16);
      tblq[((size_t)grow * 8 + h) * 16 + lp] = ov;
    }
  }
}

// ---------------- K3: bilinear core, LDS-staged levels 2+3 ----------------
// v3: 2720 fat blocks (1024 thr), batch-affine (bx&7 -> XCD L2 keeps value slice).
// Stage value rows 5120..5439 (levels 2+3, 320 rows x 512B = 160KB) in dynamic LDS,
// XOR-swizzled by (row&7) at 64B granularity. Slot groups s1/s3 are exactly
// levels 2/3 -> full-wave ds_read_b64, no divergence. Halves L2 gather traffic.
__global__ __launch_bounds__(1024) void core_kernel(
    const ushort* __restrict__ value16, const uint4* __restrict__ tblq,
    uint* __restrict__ coreo32) {
  extern __shared__ char lds[];        // 163840 B
  const int bx = blockIdx.x;           // 2720
  const int b = bx & 7;                // XCD-affine batch slice
  const int tile = bx >> 3;            // 0..339 (16 rows each)
  const int t = threadIdx.x;

  // ---- stage levels 2+3 into LDS (swizzled at 16B-unit granularity) ----
  {
    const char* src = (const char*)value16 + ((size_t)b * 5440 + 5120) * 512;
#pragma unroll
    for (int i = 0; i < 10; ++i) {
      int u = t + (i << 10);           // 0..10239 16B-units
      int row = u >> 5, c = u & 31;
      uint4 d = *(const uint4*)(src + (size_t)u * 16);
      *(uint4*)(lds + row * 512 + ((c ^ ((row & 7) << 2)) << 4)) = d;
    }
  }
  __syncthreads();

  const int w = t >> 6, lane = t & 63;
  const int s = lane >> 3, g = lane & 7;
  const uint g8 = (uint)(g << 3);
  const char* vbase = (const char*)value16 + (size_t)b * (LQ * 512);
  const uintx4* tb = (const uintx4*)tblq;
  const int bq = b * LQ + tile * 16;

  for (int it = 0; it < 4; ++it) {
    const int combo = (it << 4) + w;   // 0..63
    const int h = combo & 7;
    const int pr = combo >> 3;         // 0..7
    const int brow0 = bq + pr * 2;
    const size_t sb = ((size_t)brow0 * 8 + h) * 16;

    uintx4 s0 = __builtin_nontemporal_load(tb + sb + s);
    uintx4 s1 = __builtin_nontemporal_load(tb + sb + 8 + s);
    uintx4 s2 = __builtin_nontemporal_load(tb + sb + 128 + s);
    uintx4 s3 = __builtin_nontemporal_load(tb + sb + 136 + s);

    const char* vbh = vbase + (h << 6);
    // global gathers: levels 0/1 (idx < 5120), slot groups s0/s2
    uint2 va[8];
#define GLO(d, idx16) d = *(const uint2*)(vbh + (((uint)(idx16) << 9) + g8))
    GLO(va[0], (s0[0] & 0xFFFFu)); GLO(va[1], (s0[0] >> 16));
    GLO(va[2], (s0[1] & 0xFFFFu)); GLO(va[3], (s0[1] >> 16));
    GLO(va[4], (s2[0] & 0xFFFFu)); GLO(va[5], (s2[0] >> 16));
    GLO(va[6], (s2[1] & 0xFFFFu)); GLO(va[7], (s2[1] >> 16));
#undef GLO
    // LDS gathers: levels 2/3 (idx >= 5120), slot groups s1/s3
    uint2 vl[8];
#define LDO(d, idx16) { uint r_ = (uint)(idx16) - 5120u; \
    d = *(const uint2*)(lds + (r_ << 9) + (((uint)h ^ (r_ & 7u)) << 6) + g8); }
    LDO(vl[0], (s1[0] & 0xFFFFu)); LDO(vl[1], (s1[0] >> 16));
    LDO(vl[2], (s1[1] & 0xFFFFu)); LDO(vl[3], (s1[1] >> 16));
    LDO(vl[4], (s3[0] & 0xFFFFu)); LDO(vl[5], (s3[0] >> 16));
    LDO(vl[6], (s3[1] & 0xFFFFu)); LDO(vl[7], (s3[1] >> 16));
#undef LDO

    floatx2 a01 = {0.f, 0.f}, a23 = {0.f, 0.f};
    floatx2 c01 = {0.f, 0.f}, c23 = {0.f, 0.f};
    auto accum4 = [&](uint wz, uint ww, const uint2* vv, floatx2& x01, floatx2& x23) {
      const float ws[4] = {blo(wz), bhi(wz), blo(ww), bhi(ww)};
#pragma unroll
      for (int j = 0; j < 4; ++j) {
        floatx2 wj = {ws[j], ws[j]};
        floatx2 p = {blo(vv[j].x), bhi(vv[j].x)};
        floatx2 q = {blo(vv[j].y), bhi(vv[j].y)};
        x01 = __builtin_elementwise_fma(wj, p, x01);
        x23 = __builtin_elementwise_fma(wj, q, x23);
      }
    };
    accum4(s0[2], s0[3], &va[0], a01, a23);
    accum4(s1[2], s1[3], &vl[0], a01, a23);
    accum4(s2[2], s2[3], &va[4], c01, c23);
    accum4(s3[2], s3[3], &vl[4], c01, c23);

#pragma unroll
    for (int m = 8; m <= 32; m <<= 1) {
      a01.x += __shfl_xor(a01.x, m, 64);
      a01.y += __shfl_xor(a01.y, m, 64);
      a23.x += __shfl_xor(a23.x, m, 64);
      a23.y += __shfl_xor(a23.y, m, 64);
      c01.x += __shfl_xor(c01.x, m, 64);
      c01.y += __shfl_xor(c01.y, m, 64);
      c23.x += __shfl_xor(c23.x, m, 64);
      c23.y += __shfl_xor(c23.y, m, 64);
    }
    if (s == 0) {
      uint2 o0, o1;
      o0.x = (uint)f2b(a01.x) | ((uint)f2b(a01.y) << 16);
      o0.y = (uint)f2b(a23.x) | ((uint)f2b(a23.y) << 16);
      o1.x = (uint)f2b(c01.x) | ((uint)f2b(c01.y) << 16);
      o1.y = (uint)f2b(c23.x) | ((uint)f2b(c23.y) << 16);
      *(uint2*)(coreo32 + (size_t)brow0 * 128 + h * 16 + g * 2) = o0;
      *(uint2*)(coreo32 + (size_t)(brow0 + 1) * 128 + h * 16 + g * 2) = o1;
    }
  }
}

// ---------------- K4: out GEMM (A = core bf16) -> fp32 d_out ----------------
__global__ __launch_bounds__(256) void gemm_out64(
    const ushort* __restrict__ C, const ushort* __restrict__ WtU,
    const float* __restrict__ bout, float* __restrict__ out) {
  __shared__ ushort At[2048];
  __shared__ ushort Bs[4096];
  floatx4 acc[4][2];
  int row_base = blockIdx.x * 64, n0 = blockIdx.y * 128;
  tile64_mainloop<false>(C, WtU, row_base, n0, At, Bs, acc);
  const int t = threadIdx.x, lane = t & 63, wv = t >> 6;
  const int quad = lane >> 4, l15 = lane & 15;
#pragma unroll
  for (int tjj = 0; tjj < 2; ++tjj) {
    int gcol = n0 + (2 * wv + tjj) * 16 + l15;
    float b = bout[gcol];
#pragma unroll
    for (int ti = 0; ti < 4; ++ti)
#pragma unroll
      for (int reg = 0; reg < 4; ++reg) {
        int grow = row_base + ti * 16 + quad * 4 + reg;
        out[(size_t)grow * 256 + gcol] = acc[ti][tjj][reg] + b;
      }
  }
}

extern "C" void kernel_launch(void* const* d_in, const int* in_sizes, int n_in,
                              void* d_out, int out_size, void* d_ws, size_t ws_size,
                              hipStream_t stream) {
  const float* query  = (const float*)d_in[0];
  const float* refp   = (const float*)d_in[1];
  const float* inpf   = (const float*)d_in[2];
  const float* W_val  = (const float*)d_in[5];
  const float* b_val  = (const float*)d_in[6];
  const float* W_off  = (const float*)d_in[7];
  const float* b_off  = (const float*)d_in[8];
  const float* W_attn = (const float*)d_in[9];
  const float* b_attn = (const float*)d_in[10];
  const float* W_out  = (const float*)d_in[11];
  const float* b_out  = (const float*)d_in[12];

  char* ws = (char*)d_ws;
  ushort* Wt    = (ushort*)ws;                        // 458,752 B used (1 MB reserved)
  ushort* value = (ushort*)(ws + 1048576);            // 22,282,240 B (bf16)
  uint4*  tbl   = (uint4*)(ws + 23330816);            // 89,128,960 B (16 B slots)
  ushort* coreo = (ushort*)(ws + 112459776);          // 22,282,240 B (bf16)
  // peak = 134,742,016 B

  static bool attr_set = false;
  if (!attr_set) {
    hipFuncSetAttribute((const void*)core_kernel,
                        hipFuncAttributeMaxDynamicSharedMemorySize, 163840);
    attr_set = true;
  }

  dim3 blk(256);
  wcast_kernel<<<dim3(256, 4), blk, 0, stream>>>(W_val, W_off, W_attn, W_out, Wt);
  gemm_val64  <<<dim3(680, 2), blk, 0, stream>>>(inpf, Wt, b_val, value);
  gemm_oa_kernel<<<dim3(2720), blk, 0, stream>>>(query, Wt + 65536, b_off, b_attn, refp, tbl);
  core_kernel <<<dim3(2720), dim3(1024), 163840, stream>>>(value, tbl, (uint*)coreo);
  gemm_out64  <<<dim3(680, 2), blk, 0, stream>>>(coreo, Wt + 163840, b_out, (float*)d_out);
}

// Round 3
// 329.392 us; speedup vs baseline: 1.0303x; 1.0303x over previous
//
#include <hip/hip_runtime.h>

typedef unsigned short ushort;
typedef unsigned int uint;
typedef __bf16 bf16x8 __attribute__((ext_vector_type(8)));
typedef float floatx4 __attribute__((ext_vector_type(4)));
typedef float floatx2 __attribute__((ext_vector_type(2)));
typedef ushort ushort8 __attribute__((ext_vector_type(8)));
typedef uint uintx4 __attribute__((ext_vector_type(4)));

constexpr int LQ = 5440;
constexpr int ROWS = 43520;   // batch(8) * 5440

__device__ __forceinline__ ushort f2b(float f) {
  union { float f; uint i; } v; v.f = f;
  uint r = v.i + 0x7FFFu + ((v.i >> 16) & 1u);
  return (ushort)(r >> 16);
}
__device__ __forceinline__ float blo(uint u) {
  union { uint i; float f; } v; v.i = u << 16; return v.f;
}
__device__ __forceinline__ float bhi(uint u) {
  union { uint i; float f; } v; v.i = u & 0xFFFF0000u; return v.f;
}

// ---------------- weight transpose + cast: Wt[n][k] bf16 ----------------
// layout: [0]=Wval(256r) [65536]=Woff(256r)+Wattn(128r) fused 384-row block [163840]=Wout(256r)
__global__ __launch_bounds__(256) void wcast_kernel(
    const float* __restrict__ Wv, const float* __restrict__ Wo,
    const float* __restrict__ Wa, const float* __restrict__ Wu,
    ushort* __restrict__ Wt) {
  int k = threadIdx.x;    // 0..255
  int n = blockIdx.x;     // 0..255
  int m = blockIdx.y;     // 0..3
  const float* src = (m == 0) ? Wv : (m == 1) ? Wo : (m == 2) ? Wa : Wu;
  int N = (m == 2) ? 128 : 256;
  if (n >= N) return;
  size_t off = (size_t)m * 65536 - ((m == 3) ? 32768 : 0);  // 0,65536,131072,163840
  Wt[off + (size_t)n * 256 + k] = f2b(src[(size_t)k * N + n]);
}

// ---------------- 64x128 MFMA mainloop (K=256, BK=32), MFMA-order LDS ----------------
// Wave wv owns n-tiles {2wv, 2wv+1}, all 4 m-tiles. acc[ti][tjj].
template<bool F2B>
__device__ __forceinline__ void tile64_mainloop(
    const void* __restrict__ Av, const ushort* __restrict__ Bt,
    int row_base, int n0, ushort* At, ushort* Bs, floatx4 (&acc)[4][2]) {
  const int t = threadIdx.x;
  const int lane = t & 63, wv = t >> 6;
#pragma unroll
  for (int i = 0; i < 4; ++i)
#pragma unroll
    for (int j = 0; j < 2; ++j) acc[i][j] = floatx4{0.f, 0.f, 0.f, 0.f};

  for (int k0 = 0; k0 < 256; k0 += 32) {
    {
      int r = t >> 2, q = t & 3;       // 256 A-chunks, 1/thread
      int slot = ((r >> 4) * 64 + q * 16 + (r & 15)) * 8;
      if (F2B) {
        const float* ap = (const float*)Av + (size_t)(row_base + r) * 256 + k0 + q * 8;
        float4 a0 = *(const float4*)ap, a1 = *(const float4*)(ap + 4);
        ushort8 u;
        u[0] = f2b(a0.x); u[1] = f2b(a0.y); u[2] = f2b(a0.z); u[3] = f2b(a0.w);
        u[4] = f2b(a1.x); u[5] = f2b(a1.y); u[6] = f2b(a1.z); u[7] = f2b(a1.w);
        *(ushort8*)&At[slot] = u;
      } else {
        const ushort* ap = (const ushort*)Av + (size_t)(row_base + r) * 256 + k0 + q * 8;
        *(ushort8*)&At[slot] = *(const ushort8*)ap;
      }
    }
#pragma unroll
    for (int i = 0; i < 2; ++i) {      // 512 B-chunks, 2/thread
      int item = t + 256 * i;
      int nr = item >> 2, q = item & 3;
      int slot = ((nr >> 4) * 64 + q * 16 + (nr & 15)) * 8;
      *(ushort8*)&Bs[slot] = *(const ushort8*)(Bt + (size_t)(n0 + nr) * 256 + k0 + q * 8);
    }
    __syncthreads();
    bf16x8 af[4], bf[2];
#pragma unroll
    for (int ti = 0; ti < 4; ++ti)
      af[ti] = *(const bf16x8*)&At[(ti * 64 + lane) * 8];
#pragma unroll
    for (int tjj = 0; tjj < 2; ++tjj)
      bf[tjj] = *(const bf16x8*)&Bs[((2 * wv + tjj) * 64 + lane) * 8];
#pragma unroll
    for (int ti = 0; ti < 4; ++ti)
#pragma unroll
      for (int tjj = 0; tjj < 2; ++tjj)
        acc[ti][tjj] = __builtin_amdgcn_mfma_f32_16x16x32_bf16(af[ti], bf[tjj], acc[ti][tjj], 0, 0, 0);
    __syncthreads();
  }
}

// ---------------- K1: value GEMM (fp32 A, f2b in staging) -> bf16 value ----------------
__global__ __launch_bounds__(256) void gemm_val64(
    const float* __restrict__ X, const ushort* __restrict__ WtV,
    const float* __restrict__ bval, ushort* __restrict__ value16) {
  __shared__ ushort At[2048];
  __shared__ ushort Bs[4096];
  floatx4 acc[4][2];
  int row_base = blockIdx.x * 64, n0 = blockIdx.y * 128;
  tile64_mainloop<true>(X, WtV, row_base, n0, At, Bs, acc);
  const int t = threadIdx.x, lane = t & 63, wv = t >> 6;
  const int quad = lane >> 4, l15 = lane & 15;
#pragma unroll
  for (int tjj = 0; tjj < 2; ++tjj) {
    int gcol = n0 + (2 * wv + tjj) * 16 + l15;
    float b = bval[gcol];
#pragma unroll
    for (int ti = 0; ti < 4; ++ti)
#pragma unroll
      for (int reg = 0; reg < 4; ++reg) {
        int grow = row_base + ti * 16 + quad * 4 + reg;
        value16[(size_t)grow * 256 + gcol] = f2b(acc[ti][tjj][reg] + b);
      }
  }
}

// ---------------- K2: off+attn GEMM, head-pair sliced + softmax + slot finalize ----------------
// Block = (row_tile, head-pair hp). B-tiles: off {4hp..4hp+3}, attn {2hp,2hp+1}.
// Wave wv owns m-tile wv. slot = {i00|i01<<16, i10|i11<<16, w00|w01, w10|w11} (bf16*aw)
__global__ __launch_bounds__(256) void gemm_oa_kernel(
    const float* __restrict__ Q, const ushort* __restrict__ WtOA,
    const float* __restrict__ boff, const float* __restrict__ battn,
    const float* __restrict__ refp, uint4* __restrict__ tblq) {
  __shared__ ushort At[2048];
  __shared__ ushort Bs[3072];
  const int t = threadIdx.x;
  const int lane = t & 63, wv = t >> 6;
  const int quad = lane >> 4, l15 = lane & 15;
  const int bx = blockIdx.x;
  const int row_base = (bx % 680) * 64;
  const int hp = bx / 680;            // 0..3
  floatx4 accO[4], accA[2];
#pragma unroll
  for (int p = 0; p < 4; ++p) accO[p] = floatx4{0.f, 0.f, 0.f, 0.f};
#pragma unroll
  for (int q = 0; q < 2; ++q) accA[q] = floatx4{0.f, 0.f, 0.f, 0.f};

  for (int k0 = 0; k0 < 256; k0 += 32) {
    {
      int r = t >> 2, q = t & 3;      // 256 A-chunks
      const float* ap = Q + (size_t)(row_base + r) * 256 + k0 + q * 8;
      float4 a0 = *(const float4*)ap, a1 = *(const float4*)(ap + 4);
      ushort8 u;
      u[0] = f2b(a0.x); u[1] = f2b(a0.y); u[2] = f2b(a0.z); u[3] = f2b(a0.w);
      u[4] = f2b(a1.x); u[5] = f2b(a1.y); u[6] = f2b(a1.z); u[7] = f2b(a1.w);
      *(ushort8*)&At[((r >> 4) * 64 + q * 16 + (r & 15)) * 8] = u;
    }
#pragma unroll
    for (int i = 0; i < 2; ++i) {     // 384 B-chunks
      int item = t + 256 * i;
      if (item < 384) {
        int nrl = item >> 2, q = item & 3;
        int grow_ = (nrl < 64) ? (hp * 64 + nrl) : (256 + hp * 32 + (nrl - 64));
        *(ushort8*)&Bs[((nrl >> 4) * 64 + q * 16 + (nrl & 15)) * 8] =
            *(const ushort8*)(WtOA + (size_t)grow_ * 256 + k0 + q * 8);
      }
    }
    __syncthreads();
    bf16x8 af = *(const bf16x8*)&At[(wv * 64 + lane) * 8];
#pragma unroll
    for (int p = 0; p < 4; ++p) {
      bf16x8 bf = *(const bf16x8*)&Bs[(p * 64 + lane) * 8];
      accO[p] = __builtin_amdgcn_mfma_f32_16x16x32_bf16(af, bf, accO[p], 0, 0, 0);
    }
#pragma unroll
    for (int q = 0; q < 2; ++q) {
      bf16x8 bf = *(const bf16x8*)&Bs[((4 + q) * 64 + lane) * 8];
      accA[q] = __builtin_amdgcn_mfma_f32_16x16x32_bf16(af, bf, accA[q], 0, 0, 0);
    }
    __syncthreads();
  }

  // epilogue: per-thread 8 slot-units (4 reg x 2 heads)
  const int lp = l15, l = lp >> 2;
  const int wd = 64 >> l;
  const int st = (l == 0) ? 0 : (l == 1) ? 4096 : (l == 2) ? 5120 : 5376;
  const float lw = (float)wd;
  const int src = (quad << 4) | (2 * (lp & 7));
  float boO[4], boA[2];
#pragma unroll
  for (int p = 0; p < 4; ++p) boO[p] = boff[(4 * hp + p) * 16 + l15];
#pragma unroll
  for (int q = 0; q < 2; ++q) boA[q] = battn[(2 * hp + q) * 16 + l15];

#pragma unroll
  for (int reg = 0; reg < 4; ++reg) {
    int grow = row_base + wv * 16 + quad * 4 + reg;
    float rx = refp[(size_t)grow * 8 + l * 2];
    float ry = refp[(size_t)grow * 8 + l * 2 + 1];
#pragma unroll
    for (int hh = 0; hh < 2; ++hh) {
      int h = 2 * hp + hh;
      float xa = accA[hh][reg] + boA[hh];
      float m = xa;
      m = fmaxf(m, __shfl_xor(m, 1, 64));
      m = fmaxf(m, __shfl_xor(m, 2, 64));
      m = fmaxf(m, __shfl_xor(m, 4, 64));
      m = fmaxf(m, __shfl_xor(m, 8, 64));
      float e = __expf(xa - m);
      float ssum = e;
      ssum += __shfl_xor(ssum, 1, 64);
      ssum += __shfl_xor(ssum, 2, 64);
      ssum += __shfl_xor(ssum, 4, 64);
      ssum += __shfl_xor(ssum, 8, 64);
      float aw = e / ssum;
      float v0 = accO[2 * hh][reg] + boO[2 * hh];
      float v1 = accO[2 * hh + 1][reg] + boO[2 * hh + 1];
      float x_lo = __shfl(v0, src, 64),     x_hi = __shfl(v1, src, 64);
      float y_lo = __shfl(v0, src | 1, 64), y_hi = __shfl(v1, src | 1, 64);
      float xo = (lp < 8) ? x_lo : x_hi;
      float yo = (lp < 8) ? y_lo : y_hi;
      float X = rx * lw + xo - 0.5f;     // == (ref + off/W)*W - 0.5
      float Y = ry * lw + yo - 0.5f;
      float fx = floorf(X), fy = floorf(Y);
      float lx = X - fx, ly = Y - fy;
      int x0 = (int)fx, y0 = (int)fy, x1 = x0 + 1, y1 = y0 + 1;
      int cx0 = min(max(x0, 0), wd - 1), cx1 = min(max(x1, 0), wd - 1);
      int cy0 = min(max(y0, 0), wd - 1), cy1 = min(max(y1, 0), wd - 1);
      float vx0 = (x0 >= 0 && x0 < wd) ? 1.f : 0.f;
      float vx1 = (x1 >= 0 && x1 < wd) ? 1.f : 0.f;
      float vy0 = (y0 >= 0 && y0 < wd) ? 1.f : 0.f;
      float vy1 = (y1 >= 0 && y1 < wd) ? 1.f : 0.f;
      float g00 = (1.f - lx) * (1.f - ly) * vx0 * vy0 * aw;
      float g01 = lx * (1.f - ly) * vx1 * vy0 * aw;
      float g10 = (1.f - lx) * ly * vx0 * vy1 * aw;
      float g11 = lx * ly * vx1 * vy1 * aw;
      uint i00 = st + cy0 * wd + cx0, i01 = st + cy0 * wd + cx1;
      uint i10 = st + cy1 * wd + cx0, i11 = st + cy1 * wd + cx1;
      uint4 ov;
      ov.x = i00 | (i01 << 16);
      ov.y = i10 | (i11 << 16);
      ov.z = (uint)f2b(g00) | ((uint)f2b(g01) << 16);
      ov.w = (uint)f2b(g10) | ((uint)f2b(g11) << 16);
      tblq[((size_t)grow * 8 + h) * 16 + lp] = ov;
    }
  }
}

// ---------------- K3: bilinear core, v4: 2 chains in flight per wave ----------------
// Block = 4 consecutive rows x 8 heads (512 thr, wave = head). Batch-affine bx&7.
// Both row-pairs' slot loads + all 32 gathers issued before first consume:
// pair B's 16 gathers overlap pair A's FMA/reduce/store (counted vmcnt by
// register dependence). Doubles per-wave MLP vs v1; 2x longer block lifetime.
__device__ __forceinline__ void accum4p(uint wz, uint ww, const uint2* __restrict__ vv,
                                        floatx2& x01, floatx2& x23) {
  const float ws[4] = {blo(wz), bhi(wz), blo(ww), bhi(ww)};
#pragma unroll
  for (int j = 0; j < 4; ++j) {
    floatx2 wj = {ws[j], ws[j]};
    floatx2 p = {blo(vv[j].x), bhi(vv[j].x)};
    floatx2 q = {blo(vv[j].y), bhi(vv[j].y)};
    x01 = __builtin_elementwise_fma(wj, p, x01);
    x23 = __builtin_elementwise_fma(wj, q, x23);
  }
}

__device__ __forceinline__ void consume_pair(
    const uintx4& S0, const uintx4& S1, const uintx4& S2, const uintx4& S3,
    const uint2* __restrict__ V, int brow0, int h, int s, int g,
    uint* __restrict__ coreo32) {
  floatx2 a01 = {0.f, 0.f}, a23 = {0.f, 0.f};
  floatx2 c01 = {0.f, 0.f}, c23 = {0.f, 0.f};
  accum4p(S0[2], S0[3], V + 0,  a01, a23);
  accum4p(S1[2], S1[3], V + 4,  a01, a23);
  accum4p(S2[2], S2[3], V + 8,  c01, c23);
  accum4p(S3[2], S3[3], V + 12, c01, c23);
#pragma unroll
  for (int m = 8; m <= 32; m <<= 1) {
    a01.x += __shfl_xor(a01.x, m, 64);
    a01.y += __shfl_xor(a01.y, m, 64);
    a23.x += __shfl_xor(a23.x, m, 64);
    a23.y += __shfl_xor(a23.y, m, 64);
    c01.x += __shfl_xor(c01.x, m, 64);
    c01.y += __shfl_xor(c01.y, m, 64);
    c23.x += __shfl_xor(c23.x, m, 64);
    c23.y += __shfl_xor(c23.y, m, 64);
  }
  if (s == 0) {
    uint2 o0, o1;
    o0.x = (uint)f2b(a01.x) | ((uint)f2b(a01.y) << 16);
    o0.y = (uint)f2b(a23.x) | ((uint)f2b(a23.y) << 16);
    o1.x = (uint)f2b(c01.x) | ((uint)f2b(c01.y) << 16);
    o1.y = (uint)f2b(c23.x) | ((uint)f2b(c23.y) << 16);
    *(uint2*)(coreo32 + (size_t)brow0 * 128 + h * 16 + g * 2) = o0;
    *(uint2*)(coreo32 + (size_t)(brow0 + 1) * 128 + h * 16 + g * 2) = o1;
  }
}

__global__ __launch_bounds__(512) void core_kernel(
    const ushort* __restrict__ value16, const uint4* __restrict__ tblq,
    uint* __restrict__ coreo32) {
  const int bx = blockIdx.x;           // 10880
  const int b = bx & 7;                // XCD-affine batch slice
  const int tile = bx >> 3;            // 0..1359
  const int t = threadIdx.x;
  const int h = t >> 6, lane = t & 63; // wave = head
  const int s = lane >> 3, g = lane & 7;
  const uint g8 = (uint)(g << 3);
  const char* vbh = (const char*)value16 + (size_t)b * (LQ * 512) + (h << 6);
  const uintx4* tb = (const uintx4*)tblq;
  const int row0 = b * LQ + tile * 4;  // 4 rows per block
  const size_t sb = ((size_t)row0 * 8 + h) * 16 + s;

  // slot loads for both row-pairs (8 outstanding)
  uintx4 A0 = __builtin_nontemporal_load(tb + sb);
  uintx4 A1 = __builtin_nontemporal_load(tb + sb + 8);
  uintx4 A2 = __builtin_nontemporal_load(tb + sb + 128);
  uintx4 A3 = __builtin_nontemporal_load(tb + sb + 136);
  uintx4 B0 = __builtin_nontemporal_load(tb + sb + 256);
  uintx4 B1 = __builtin_nontemporal_load(tb + sb + 264);
  uintx4 B2 = __builtin_nontemporal_load(tb + sb + 384);
  uintx4 B3 = __builtin_nontemporal_load(tb + sb + 392);

  uint2 VA[16], VB[16];
#define GL(d, idx16) d = *(const uint2*)(vbh + (((uint)(idx16) << 9) + g8))
  // pair A gathers (waits A0..A3 only; B slots keep flying)
  GL(VA[0],  (A0[0] & 0xFFFFu)); GL(VA[1],  (A0[0] >> 16));
  GL(VA[2],  (A0[1] & 0xFFFFu)); GL(VA[3],  (A0[1] >> 16));
  GL(VA[4],  (A1[0] & 0xFFFFu)); GL(VA[5],  (A1[0] >> 16));
  GL(VA[6],  (A1[1] & 0xFFFFu)); GL(VA[7],  (A1[1] >> 16));
  GL(VA[8],  (A2[0] & 0xFFFFu)); GL(VA[9],  (A2[0] >> 16));
  GL(VA[10], (A2[1] & 0xFFFFu)); GL(VA[11], (A2[1] >> 16));
  GL(VA[12], (A3[0] & 0xFFFFu)); GL(VA[13], (A3[0] >> 16));
  GL(VA[14], (A3[1] & 0xFFFFu)); GL(VA[15], (A3[1] >> 16));
  // pair B gathers
  GL(VB[0],  (B0[0] & 0xFFFFu)); GL(VB[1],  (B0[0] >> 16));
  GL(VB[2],  (B0[1] & 0xFFFFu)); GL(VB[3],  (B0[1] >> 16));
  GL(VB[4],  (B1[0] & 0xFFFFu)); GL(VB[5],  (B1[0] >> 16));
  GL(VB[6],  (B1[1] & 0xFFFFu)); GL(VB[7],  (B1[1] >> 16));
  GL(VB[8],  (B2[0] & 0xFFFFu)); GL(VB[9],  (B2[0] >> 16));
  GL(VB[10], (B2[1] & 0xFFFFu)); GL(VB[11], (B2[1] >> 16));
  GL(VB[12], (B3[0] & 0xFFFFu)); GL(VB[13], (B3[0] >> 16));
  GL(VB[14], (B3[1] & 0xFFFFu)); GL(VB[15], (B3[1] >> 16));
#undef GL

  consume_pair(A0, A1, A2, A3, VA, row0,     h, s, g, coreo32);
  consume_pair(B0, B1, B2, B3, VB, row0 + 2, h, s, g, coreo32);
}

// ---------------- K4: out GEMM (A = core bf16) -> fp32 d_out ----------------
__global__ __launch_bounds__(256) void gemm_out64(
    const ushort* __restrict__ C, const ushort* __restrict__ WtU,
    const float* __restrict__ bout, float* __restrict__ out) {
  __shared__ ushort At[2048];
  __shared__ ushort Bs[4096];
  floatx4 acc[4][2];
  int row_base = blockIdx.x * 64, n0 = blockIdx.y * 128;
  tile64_mainloop<false>(C, WtU, row_base, n0, At, Bs, acc);
  const int t = threadIdx.x, lane = t & 63, wv = t >> 6;
  const int quad = lane >> 4, l15 = lane & 15;
#pragma unroll
  for (int tjj = 0; tjj < 2; ++tjj) {
    int gcol = n0 + (2 * wv + tjj) * 16 + l15;
    float b = bout[gcol];
#pragma unroll
    for (int ti = 0; ti < 4; ++ti)
#pragma unroll
      for (int reg = 0; reg < 4; ++reg) {
        int grow = row_base + ti * 16 + quad * 4 + reg;
        out[(size_t)grow * 256 + gcol] = acc[ti][tjj][reg] + b;
      }
  }
}

extern "C" void kernel_launch(void* const* d_in, const int* in_sizes, int n_in,
                              void* d_out, int out_size, void* d_ws, size_t ws_size,
                              hipStream_t stream) {
  const float* query  = (const float*)d_in[0];
  const float* refp   = (const float*)d_in[1];
  const float* inpf   = (const float*)d_in[2];
  const float* W_val  = (const float*)d_in[5];
  const float* b_val  = (const float*)d_in[6];
  const float* W_off  = (const float*)d_in[7];
  const float* b_off  = (const float*)d_in[8];
  const float* W_attn = (const float*)d_in[9];
  const float* b_attn = (const float*)d_in[10];
  const float* W_out  = (const float*)d_in[11];
  const float* b_out  = (const float*)d_in[12];

  char* ws = (char*)d_ws;
  ushort* Wt    = (ushort*)ws;                        // 458,752 B used (1 MB reserved)
  ushort* value = (ushort*)(ws + 1048576);            // 22,282,240 B (bf16)
  uint4*  tbl   = (uint4*)(ws + 23330816);            // 89,128,960 B (16 B slots)
  ushort* coreo = (ushort*)(ws + 112459776);          // 22,282,240 B (bf16)
  // peak = 134,742,016 B

  dim3 blk(256);
  wcast_kernel<<<dim3(256, 4), blk, 0, stream>>>(W_val, W_off, W_attn, W_out, Wt);
  gemm_val64  <<<dim3(680, 2), blk, 0, stream>>>(inpf, Wt, b_val, value);
  gemm_oa_kernel<<<dim3(2720), blk, 0, stream>>>(query, Wt + 65536, b_off, b_attn, refp, tbl);
  core_kernel <<<dim3(10880), dim3(512), 0, stream>>>(value, tbl, (uint*)coreo);
  gemm_out64  <<<dim3(680, 2), blk, 0, stream>>>(coreo, Wt + 163840, b_out, (float*)d_out);
}